// Round 3
// baseline (284.624 us; speedup 1.0000x reference)
//
#include <hip/hip_runtime.h>

#define N_NODES 10000
#define N_EDGES 160000
#define MUL0 16
#define MUL1 8
#define H_EDGE 64
#define W_NUMEL 576
#define EPS 1e-5f

#define BM 64          // edges per block
#define THREADS 256
#define WP 584         // padded row length (ushort) of W_lds tile

#define INV16 0.25f
#define INV24 0.20412414523193154f   // 1/sqrt(24)
#define INV8  0.3535533905932738f    // 1/sqrt(8)

typedef __attribute__((ext_vector_type(8))) short bf16x8;
typedef __attribute__((ext_vector_type(4))) short bf16x4;
typedef __attribute__((ext_vector_type(4))) float f32x4;

__device__ __forceinline__ unsigned short f2bf(float x) {
    union { float f; unsigned int u; } c; c.f = x;
    unsigned int r = c.u + 0x7fffu + ((c.u >> 16) & 1u);   // RNE
    return (unsigned short)(r >> 16);
}
__device__ __forceinline__ float bf2f(unsigned short u) {
    union { unsigned int i; float f; } c; c.i = ((unsigned int)u) << 16; return c.f;
}

// fragment k-index for 16x16x32 bf16: k = 32*ks + 16*(j>>2) + 4*(lane>>4) + (j&3)

// -----------------------------------------------------------------------------
// Prep: zero accumulators + pack W1^T / W2^T into per-lane MFMA A-fragment order.
// -----------------------------------------------------------------------------
__global__ __launch_bounds__(256)
void prep_frags(const float* __restrict__ W1, const float* __restrict__ W2,
                unsigned short* __restrict__ W1F, unsigned short* __restrict__ W2F,
                float* __restrict__ zero_base)
{
    const int idx = blockIdx.x * 256 + threadIdx.x;
    const int ztot = N_NODES * 40 + N_NODES + 40;
    for (int i = idx; i < ztot; i += 256 * 256) zero_base[i] = 0.0f;
    if (idx >= 4096 + 36864) return;
    if (idx < 4096) {
        const int j = idx & 7, l = (idx >> 3) & 63, ks = (idx >> 9) & 1, mt = idx >> 10;
        const int k = 32 * ks + 16 * (j >> 2) + 4 * (l >> 4) + (j & 3);
        const int col = 16 * mt + (l & 15);
        W1F[idx] = f2bf(W1[k * 64 + col]);
    } else {
        const int i2 = idx - 4096;
        const int j = i2 & 7, l = (i2 >> 3) & 63, ks = (i2 >> 9) & 1, nt = i2 >> 10;
        const int k = 32 * ks + 16 * (j >> 2) + 4 * (l >> 4) + (j & 3);
        const int col = 16 * nt + (l & 15);
        W2F[i2] = f2bf(W2[k * 576 + col]);
    }
}

// -----------------------------------------------------------------------------
// Fused edge kernel (MFMA): h^T = relu(W1^T ef^T + b1), w^T = W2^T h^T + b2,
// TP + atomic scatter.  LDS: union { [ef 8KB | h 8KB] , W-tile bf16 18.7KB }
// -----------------------------------------------------------------------------
__global__ __launch_bounds__(THREADS, 5)
void fused_edge_kernel(const float* __restrict__ atom,   // [N_NODES*40]
                       const float* __restrict__ ef,     // [N_EDGES*64]
                       const float* __restrict__ esh,    // [N_EDGES*4]
                       const int*   __restrict__ e_dst,
                       const int*   __restrict__ e_src,
                       const unsigned short* __restrict__ W1F,
                       const float* __restrict__ b1,
                       const unsigned short* __restrict__ W2F,
                       const float* __restrict__ b2,
                       float* __restrict__ sums,         // [N_NODES*40]
                       float* __restrict__ cnts)         // [N_NODES]
{
    __shared__ __align__(16) char lds[16 * WP * 2];      // 18688 B
    unsigned short* ef_lds = (unsigned short*)lds;            // [64][64] swizzled
    unsigned short* h_lds  = (unsigned short*)(lds + 8192);   // [64][64] swizzled
    unsigned short* W_lds  = (unsigned short*)lds;            // [16][WP] (after GEMMs)

    const int tid = threadIdx.x;
    const int l   = tid & 63;        // lane
    const int wv  = tid >> 6;        // wave 0..3
    const int e0  = blockIdx.x * BM;
    const int h4  = l >> 4;          // 0..3
    const int e16 = l & 15;

    // ---- stage ef tile -> LDS bf16 (swizzled) ----
    {
        const int edge = tid >> 2;           // 0..63
        const int fq   = tid & 3;
        #pragma unroll
        for (int ii = 0; ii < 4; ++ii) {
            const int f = fq * 16 + ii * 4;
            const float4 v = *(const float4*)(ef + (size_t)(e0 + edge) * 64 + f);
            bf16x4 p;
            p[0] = (short)f2bf(v.x); p[1] = (short)f2bf(v.y);
            p[2] = (short)f2bf(v.z); p[3] = (short)f2bf(v.w);
            const int addr = ((edge << 7) + (f << 1)) ^ ((edge & 7) << 4);
            *(bf16x4*)((char*)ef_lds + addr) = p;
        }
    }
    __syncthreads();

    // ---- GEMM1: wave wv computes h^T cols (edges) [16wv,16wv+16) ----
    {
        const int edge = 16 * wv + e16;
        bf16x8 bE[2];
        #pragma unroll
        for (int ks = 0; ks < 2; ++ks) {
            const int f0 = 32 * ks + 4 * h4;
            const int a0 = ((edge << 7) + (f0 << 1)) ^ ((edge & 7) << 4);
            const int a1 = ((edge << 7) + ((f0 + 16) << 1)) ^ ((edge & 7) << 4);
            bf16x4 lo = *(const bf16x4*)((const char*)ef_lds + a0);
            bf16x4 hi = *(const bf16x4*)((const char*)ef_lds + a1);
            bf16x8 b;
            b[0]=lo[0]; b[1]=lo[1]; b[2]=lo[2]; b[3]=lo[3];
            b[4]=hi[0]; b[5]=hi[1]; b[6]=hi[2]; b[7]=hi[3];
            bE[ks] = b;
        }
        #pragma unroll
        for (int mti = 0; mti < 4; ++mti) {
            f32x4 a = *(const f32x4*)(b1 + 16 * mti + 4 * h4);
            #pragma unroll
            for (int ks = 0; ks < 2; ++ks) {
                const bf16x8 aW = *(const bf16x8*)(W1F + ((size_t)(mti * 2 + ks) * 64 + l) * 8);
                a = __builtin_amdgcn_mfma_f32_16x16x32_bf16(aW, bE[ks], a, 0, 0, 0);
            }
            bf16x4 hw;
            #pragma unroll
            for (int r = 0; r < 4; ++r) hw[r] = (short)f2bf(fmaxf(a[r], 0.0f));
            const int n0 = 16 * mti + 4 * h4;
            const int addr = ((edge << 7) + (n0 << 1)) ^ ((edge & 7) << 4);
            *(bf16x4*)((char*)h_lds + addr) = hw;
        }
    }
    __syncthreads();

    // ---- GEMM2: wave wv owns N-tiles nt = 9wv..9wv+8, all 4 edge tiles ----
    bf16x8 bH[4][2];
    #pragma unroll
    for (int mt = 0; mt < 4; ++mt) {
        const int edge = 16 * mt + e16;
        #pragma unroll
        for (int ks = 0; ks < 2; ++ks) {
            const int f0 = 32 * ks + 4 * h4;
            const int a0 = ((edge << 7) + (f0 << 1)) ^ ((edge & 7) << 4);
            const int a1 = ((edge << 7) + ((f0 + 16) << 1)) ^ ((edge & 7) << 4);
            bf16x4 lo = *(const bf16x4*)((const char*)h_lds + a0);
            bf16x4 hi = *(const bf16x4*)((const char*)h_lds + a1);
            bf16x8 b;
            b[0]=lo[0]; b[1]=lo[1]; b[2]=lo[2]; b[3]=lo[3];
            b[4]=hi[0]; b[5]=hi[1]; b[6]=hi[2]; b[7]=hi[3];
            bH[mt][ks] = b;
        }
    }

    f32x4 acc[9][4];
    #pragma unroll
    for (int t = 0; t < 9; ++t) {
        const int nt = 9 * wv + t;
        const f32x4 bias = *(const f32x4*)(b2 + 16 * nt + 4 * h4);
        #pragma unroll
        for (int mt = 0; mt < 4; ++mt) acc[t][mt] = bias;
        #pragma unroll
        for (int ks = 0; ks < 2; ++ks) {
            const bf16x8 aW = *(const bf16x8*)(W2F + ((size_t)(nt * 2 + ks) * 64 + l) * 8);
            #pragma unroll
            for (int mt = 0; mt < 4; ++mt)
                acc[t][mt] = __builtin_amdgcn_mfma_f32_16x16x32_bf16(aW, bH[mt][ks], acc[t][mt], 0, 0, 0);
        }
    }

    // ---- TP + scatter per 16-edge tile (W tile bf16, [edge][nw]) ----
    #pragma unroll
    for (int mt = 0; mt < 4; ++mt) {
        __syncthreads();   // previous readers done; (first iter: ef/h dead, bH in regs)
        #pragma unroll
        for (int t = 0; t < 9; ++t) {
            const int nt = 9 * wv + t;
            bf16x4 wp;
            #pragma unroll
            for (int r = 0; r < 4; ++r) wp[r] = (short)f2bf(acc[t][mt][r]);
            *(bf16x4*)&W_lds[e16 * WP + 16 * nt + 4 * h4] = wp;
        }
        __syncthreads();

        const int r   = tid & 15;
        const int el  = tid >> 4;                  // 0..15
        const int base= l & 48;                    // wave-local 16-lane group base
        const int e   = e0 + 16 * mt + el;
        const int dst = e_dst[e];
        const int src = e_src[e];
        const float* x = atom + (size_t)dst * 40;
        const float sh0 = esh[e * 4 + 0];
        const float s1x = esh[e * 4 + 1];
        const float s1y = esh[e * 4 + 2];
        const float s1z = esh[e * 4 + 3];
        #define WW(nw) bf2f(W_lds[el * WP + (nw)])

        const int   r8 = r & 7;
        const float xs = x[r];                     // x0[r]
        const float v0 = x[16 + 3 * r8];
        const float v1 = x[17 + 3 * r8];
        const float v2 = x[18 + 3 * r8];
        const float d  = v0 * s1x + v1 * s1y + v2 * s1z;

        float s1 = 0.f, s2 = 0.f, p = 0.f, q0 = 0.f, q1 = 0.f, q2 = 0.f;
        #pragma unroll
        for (int i = 0; i < 16; ++i) {
            const float xv = __shfl(xs, base + i);
            s1 = fmaf(xv, WW(i * 16 + r), s1);
            p  = fmaf(xv, WW(256 + i * 8 + r8), p);
        }
        #pragma unroll
        for (int i = 0; i < 8; ++i) {
            const float dv = __shfl(d, base + i);
            s2 = fmaf(dv, WW(448 + i * 16 + r), s2);
            const float av = WW(384 + i * 8 + r8);
            q0 = fmaf(__shfl(v0, base + i), av, q0);
            q1 = fmaf(__shfl(v1, base + i), av, q1);
            q2 = fmaf(__shfl(v2, base + i), av, q2);
        }
        atomicAdd(&sums[(size_t)src * 40 + r], INV16 * sh0 * s1 + INV24 * s2);
        if (r < 8) {
            const float ps = INV16 * p;
            const float qs = INV8 * sh0;
            atomicAdd(&sums[(size_t)src * 40 + 16 + 3 * r + 0], s1x * ps + qs * q0);
            atomicAdd(&sums[(size_t)src * 40 + 16 + 3 * r + 1], s1y * ps + qs * q1);
            atomicAdd(&sums[(size_t)src * 40 + 16 + 3 * r + 2], s1z * ps + qs * q2);
        }
        if (r == 0) atomicAdd(&cnts[src], 1.0f);
        #undef WW
    }
}

// -----------------------------------------------------------------------------
// y = sums/max(cnt,1) + atom; accumulate BN statistics (wave-shuffle reduced)
// -----------------------------------------------------------------------------
__global__ __launch_bounds__(256)
void finalize_stats_kernel(const float* __restrict__ sums,
                           const float* __restrict__ cnts,
                           const float* __restrict__ atom,
                           float* __restrict__ y,
                           float* __restrict__ stats)
{
    const int n = blockIdx.x * blockDim.x + threadIdx.x;
    float yv[40];
    if (n < N_NODES) {
        const float rinv = 1.0f / fmaxf(cnts[n], 1.0f);
        const float4* s4 = (const float4*)(sums + (size_t)n * 40);
        const float4* a4 = (const float4*)(atom + (size_t)n * 40);
        float4* y4 = (float4*)(y + (size_t)n * 40);
        #pragma unroll
        for (int r = 0; r < 10; ++r) {
            const float4 sv = s4[r];
            const float4 av = a4[r];
            float4 o;
            o.x = sv.x * rinv + av.x;
            o.y = sv.y * rinv + av.y;
            o.z = sv.z * rinv + av.z;
            o.w = sv.w * rinv + av.w;
            y4[r] = o;
            yv[r * 4 + 0] = o.x; yv[r * 4 + 1] = o.y;
            yv[r * 4 + 2] = o.z; yv[r * 4 + 3] = o.w;
        }
    } else {
        #pragma unroll
        for (int s = 0; s < 40; ++s) yv[s] = 0.0f;
    }

    float contrib[40];
    #pragma unroll
    for (int j = 0; j < 16; ++j) {
        contrib[j]      = yv[j];
        contrib[16 + j] = yv[j] * yv[j];
    }
    #pragma unroll
    for (int j = 0; j < 8; ++j) {
        const float vx = yv[16 + 3 * j], vy = yv[17 + 3 * j], vz = yv[18 + 3 * j];
        contrib[32 + j] = (vx * vx + vy * vy + vz * vz) * (1.0f / 3.0f);
    }
    #pragma unroll
    for (int s = 0; s < 40; ++s) {
        float v = contrib[s];
        #pragma unroll
        for (int off = 32; off > 0; off >>= 1) v += __shfl_xor(v, off);
        if ((threadIdx.x & 63) == 0) atomicAdd(&stats[s], v);
    }
}

__global__ __launch_bounds__(256)
void apply_bn_kernel(float* __restrict__ y,
                     const float* __restrict__ stats,
                     const float* __restrict__ bnw,
                     const float* __restrict__ bnb)
{
    const int idx = blockIdx.x * blockDim.x + threadIdx.x;
    if (idx >= N_NODES * 40) return;
    const int o = idx % 40;
    const float invN = 1.0f / (float)N_NODES;
    const float v = y[idx];
    float out;
    if (o < MUL0) {
        const float mean  = stats[o] * invN;
        const float var   = stats[16 + o] * invN - mean * mean;
        const float scale = rsqrtf(var + EPS) * bnw[o];
        out = (v - mean) * scale + bnb[o];
    } else {
        const int j = (o - 16) / 3;
        const float vn = stats[32 + j] * invN;
        out = v * (rsqrtf(vn + EPS) * bnw[16 + j]);
    }
    y[idx] = out;
}

// -----------------------------------------------------------------------------
extern "C" void kernel_launch(void* const* d_in, const int* in_sizes, int n_in,
                              void* d_out, int out_size, void* d_ws, size_t ws_size,
                              hipStream_t stream)
{
    const float* atom = (const float*)d_in[0];
    const float* ef   = (const float*)d_in[1];
    const float* esh  = (const float*)d_in[2];
    const int*   eidx = (const int*)d_in[3];
    const float* W1   = (const float*)d_in[4];
    const float* b1   = (const float*)d_in[5];
    const float* W2   = (const float*)d_in[6];
    const float* b2   = (const float*)d_in[7];
    const float* bnw  = (const float*)d_in[8];
    const float* bnb  = (const float*)d_in[9];
    float* out = (float*)d_out;

    float* sums  = (float*)d_ws;                       // N_NODES*40
    float* cnts  = sums + (size_t)N_NODES * 40;        // N_NODES
    float* stats = cnts + N_NODES;                     // 40
    unsigned short* W1F = (unsigned short*)(stats + 40);   // 4096 bf16
    unsigned short* W2F = W1F + 4096;                      // 36864 bf16

    const int* e_dst = eidx;
    const int* e_src = eidx + N_EDGES;

    prep_frags<<<256, 256, 0, stream>>>(W1, W2, W1F, W2F, sums);

    fused_edge_kernel<<<N_EDGES / BM, THREADS, 0, stream>>>(
        atom, ef, esh, e_dst, e_src, W1F, b1, W2F, b2, sums, cnts);

    finalize_stats_kernel<<<(N_NODES + 255) / 256, 256, 0, stream>>>(
        sums, cnts, atom, out, stats);

    apply_bn_kernel<<<(N_NODES * 40 + 255) / 256, 256, 0, stream>>>(
        out, stats, bnw, bnb);
}

// Round 4
// 170.239 us; speedup vs baseline: 1.6719x; 1.6719x over previous
//
#include <hip/hip_runtime.h>

#define N_NODES 10000
#define N_EDGES 160000
#define MUL0 16
#define MUL1 8
#define H_EDGE 64
#define W_NUMEL 576
#define EPS 1e-5f

#define BM 32          // edges per block (2 edge-tiles)
#define THREADS 256
#define WP 592         // padded row length (ushort) of W_lds tile; 592*2B=1184B=296 words; 296%32=8 banks

#define INV16 0.25f
#define INV24 0.20412414523193154f   // 1/sqrt(24)
#define INV8  0.3535533905932738f    // 1/sqrt(8)

typedef __attribute__((ext_vector_type(8))) short bf16x8;
typedef __attribute__((ext_vector_type(4))) short bf16x4;
typedef __attribute__((ext_vector_type(4))) float f32x4;

__device__ __forceinline__ unsigned short f2bf(float x) {
    union { float f; unsigned int u; } c; c.f = x;
    unsigned int r = c.u + 0x7fffu + ((c.u >> 16) & 1u);   // RNE
    return (unsigned short)(r >> 16);
}
__device__ __forceinline__ float bf2f(unsigned short u) {
    union { unsigned int i; float f; } c; c.i = ((unsigned int)u) << 16; return c.f;
}

// fragment k-index for 16x16x32 bf16: k = 32*ks + 16*(j>>2) + 4*(lane>>4) + (j&3)

// -----------------------------------------------------------------------------
// Prep: zero accumulators + pack W1^T / W2^T into per-lane MFMA A-fragment order.
// -----------------------------------------------------------------------------
__global__ __launch_bounds__(256)
void prep_frags(const float* __restrict__ W1, const float* __restrict__ W2,
                unsigned short* __restrict__ W1F, unsigned short* __restrict__ W2F,
                float* __restrict__ zero_base)
{
    const int idx = blockIdx.x * 256 + threadIdx.x;
    const int ztot = N_NODES * 40 + N_NODES + 40;
    for (int i = idx; i < ztot; i += 256 * 256) zero_base[i] = 0.0f;
    if (idx >= 4096 + 36864) return;
    if (idx < 4096) {
        const int j = idx & 7, l = (idx >> 3) & 63, ks = (idx >> 9) & 1, mt = idx >> 10;
        const int k = 32 * ks + 16 * (j >> 2) + 4 * (l >> 4) + (j & 3);
        const int col = 16 * mt + (l & 15);
        W1F[idx] = f2bf(W1[k * 64 + col]);
    } else {
        const int i2 = idx - 4096;
        const int j = i2 & 7, l = (i2 >> 3) & 63, ks = (i2 >> 9) & 1, nt = i2 >> 10;
        const int k = 32 * ks + 16 * (j >> 2) + 4 * (l >> 4) + (j & 3);
        const int col = 16 * nt + (l & 15);
        W2F[i2] = f2bf(W2[k * 576 + col]);
    }
}

// -----------------------------------------------------------------------------
// Fused edge kernel (MFMA): h^T = relu(W1^T ef^T + b1), w^T = W2^T h^T + b2,
// TP + atomic scatter.  BM=32 edges/block; acc[9][2] keeps VGPR < 128 (4 w/EU).
// LDS: union { ef 4KB | h 4KB , W-tile bf16 18.9KB }
// -----------------------------------------------------------------------------
__global__ __launch_bounds__(THREADS, 4)
void fused_edge_kernel(const float* __restrict__ atom,   // [N_NODES*40]
                       const float* __restrict__ ef,     // [N_EDGES*64]
                       const float* __restrict__ esh,    // [N_EDGES*4]
                       const int*   __restrict__ e_dst,
                       const int*   __restrict__ e_src,
                       const unsigned short* __restrict__ W1F,
                       const float* __restrict__ b1,
                       const unsigned short* __restrict__ W2F,
                       const float* __restrict__ b2,
                       float* __restrict__ sums,         // [N_NODES*40]
                       float* __restrict__ cnts)         // [N_NODES]
{
    __shared__ __align__(16) char lds[16 * WP * 2];           // 18944 B
    unsigned short* ef_lds = (unsigned short*)lds;            // [32][64] swizzled
    unsigned short* h_lds  = (unsigned short*)(lds + 4096);   // [32][64] swizzled
    unsigned short* W_lds  = (unsigned short*)lds;            // [16][WP] (after GEMMs)

    const int tid = threadIdx.x;
    const int l   = tid & 63;        // lane
    const int wv  = tid >> 6;        // wave 0..3
    const int e0  = blockIdx.x * BM;
    const int h4  = l >> 4;          // 0..3
    const int e16 = l & 15;

    // ---- stage ef tile -> LDS bf16 (swizzled): 32 edges x 64 f ----
    #pragma unroll
    for (int rr = 0; rr < 2; ++rr) {
        const int i    = tid + rr * 256;     // 0..511
        const int edge = i >> 4;             // 0..31
        const int f    = (i & 15) * 4;
        const float4 v = *(const float4*)(ef + (size_t)(e0 + edge) * 64 + f);
        bf16x4 p;
        p[0] = (short)f2bf(v.x); p[1] = (short)f2bf(v.y);
        p[2] = (short)f2bf(v.z); p[3] = (short)f2bf(v.w);
        const int addr = ((edge << 7) + (f << 1)) ^ ((edge & 7) << 4);
        *(bf16x4*)((char*)ef_lds + addr) = p;
    }
    __syncthreads();

    // ---- GEMM1: wave wv: edge-tile et=wv>>1, row-tiles {2(wv&1), 2(wv&1)+1} ----
    {
        const int et   = wv >> 1;
        const int rt   = wv & 1;
        const int edge = 16 * et + e16;
        bf16x8 bE[2];
        #pragma unroll
        for (int ks = 0; ks < 2; ++ks) {
            const int f0 = 32 * ks + 4 * h4;
            const int a0 = ((edge << 7) + (f0 << 1)) ^ ((edge & 7) << 4);
            const int a1 = ((edge << 7) + ((f0 + 16) << 1)) ^ ((edge & 7) << 4);
            bf16x4 lo = *(const bf16x4*)((const char*)ef_lds + a0);
            bf16x4 hi = *(const bf16x4*)((const char*)ef_lds + a1);
            bf16x8 b;
            b[0]=lo[0]; b[1]=lo[1]; b[2]=lo[2]; b[3]=lo[3];
            b[4]=hi[0]; b[5]=hi[1]; b[6]=hi[2]; b[7]=hi[3];
            bE[ks] = b;
        }
        #pragma unroll
        for (int mi = 0; mi < 2; ++mi) {
            const int mti = 2 * rt + mi;
            f32x4 a = *(const f32x4*)(b1 + 16 * mti + 4 * h4);
            #pragma unroll
            for (int ks = 0; ks < 2; ++ks) {
                const bf16x8 aW = *(const bf16x8*)(W1F + ((size_t)(mti * 2 + ks) * 64 + l) * 8);
                a = __builtin_amdgcn_mfma_f32_16x16x32_bf16(aW, bE[ks], a, 0, 0, 0);
            }
            bf16x4 hw;
            #pragma unroll
            for (int r = 0; r < 4; ++r) hw[r] = (short)f2bf(fmaxf(a[r], 0.0f));
            const int n0 = 16 * mti + 4 * h4;
            const int addr = ((edge << 7) + (n0 << 1)) ^ ((edge & 7) << 4);
            *(bf16x4*)((char*)h_lds + addr) = hw;
        }
    }
    __syncthreads();

    // ---- load B-fragments of h for both edge tiles ----
    bf16x8 bH[2][2];
    #pragma unroll
    for (int mt = 0; mt < 2; ++mt) {
        const int edge = 16 * mt + e16;
        #pragma unroll
        for (int ks = 0; ks < 2; ++ks) {
            const int f0 = 32 * ks + 4 * h4;
            const int a0 = ((edge << 7) + (f0 << 1)) ^ ((edge & 7) << 4);
            const int a1 = ((edge << 7) + ((f0 + 16) << 1)) ^ ((edge & 7) << 4);
            bf16x4 lo = *(const bf16x4*)((const char*)h_lds + a0);
            bf16x4 hi = *(const bf16x4*)((const char*)h_lds + a1);
            bf16x8 b;
            b[0]=lo[0]; b[1]=lo[1]; b[2]=lo[2]; b[3]=lo[3];
            b[4]=hi[0]; b[5]=hi[1]; b[6]=hi[2]; b[7]=hi[3];
            bH[mt][ks] = b;
        }
    }
    __syncthreads();   // h_lds dead -> W_lds region reusable

    // ---- GEMM2: wave wv owns N-tiles nt = 9wv..9wv+8, both edge tiles ----
    f32x4 acc[9][2];
    #pragma unroll
    for (int t = 0; t < 9; ++t) {
        const int nt = 9 * wv + t;
        const f32x4 bias = *(const f32x4*)(b2 + 16 * nt + 4 * h4);
        acc[t][0] = bias;
        acc[t][1] = bias;
        #pragma unroll
        for (int ks = 0; ks < 2; ++ks) {
            const bf16x8 aW = *(const bf16x8*)(W2F + ((size_t)(nt * 2 + ks) * 64 + l) * 8);
            acc[t][0] = __builtin_amdgcn_mfma_f32_16x16x32_bf16(aW, bH[0][ks], acc[t][0], 0, 0, 0);
            acc[t][1] = __builtin_amdgcn_mfma_f32_16x16x32_bf16(aW, bH[1][ks], acc[t][1], 0, 0, 0);
        }
    }

    // ---- TP + scatter per 16-edge tile (W tile bf16, [edge][nw]) ----
    #pragma unroll
    for (int mt = 0; mt < 2; ++mt) {
        #pragma unroll
        for (int t = 0; t < 9; ++t) {
            const int nt = 9 * wv + t;
            bf16x4 wp;
            #pragma unroll
            for (int r = 0; r < 4; ++r) wp[r] = (short)f2bf(acc[t][mt][r]);
            *(bf16x4*)&W_lds[e16 * WP + 16 * nt + 4 * h4] = wp;
        }
        __syncthreads();

        const int r    = tid & 15;
        const int el   = tid >> 4;                 // 0..15
        const int base = l & 48;                   // wave-local 16-lane group base
        const int e    = e0 + 16 * mt + el;
        const int dst  = e_dst[e];
        const int src  = e_src[e];
        const float* x = atom + (size_t)dst * 40;
        const float4 shv = *(const float4*)(esh + (size_t)e * 4);
        const float sh0 = shv.x, s1x = shv.y, s1y = shv.z, s1z = shv.w;
        #define WW(nw) bf2f(W_lds[el * WP + (nw)])

        const int   r8 = r & 7;
        const float xs = x[r];                     // x0[r]
        const float v0 = x[16 + 3 * r8];
        const float v1 = x[17 + 3 * r8];
        const float v2 = x[18 + 3 * r8];
        const float d  = v0 * s1x + v1 * s1y + v2 * s1z;

        float s1 = 0.f, s2 = 0.f, p = 0.f, q0 = 0.f, q1 = 0.f, q2 = 0.f;
        #pragma unroll
        for (int i = 0; i < 16; ++i) {
            const float xv = __shfl(xs, base + i);
            s1 = fmaf(xv, WW(i * 16 + r), s1);
            p  = fmaf(xv, WW(256 + i * 8 + r8), p);
        }
        #pragma unroll
        for (int i = 0; i < 8; ++i) {
            const float dv = __shfl(d, base + i);
            s2 = fmaf(dv, WW(448 + i * 16 + r), s2);
            const float av = WW(384 + i * 8 + r8);
            q0 = fmaf(__shfl(v0, base + i), av, q0);
            q1 = fmaf(__shfl(v1, base + i), av, q1);
            q2 = fmaf(__shfl(v2, base + i), av, q2);
        }
        atomicAdd(&sums[(size_t)src * 40 + r], INV16 * sh0 * s1 + INV24 * s2);
        if (r < 8) {
            const float ps = INV16 * p;
            const float qs = INV8 * sh0;
            atomicAdd(&sums[(size_t)src * 40 + 16 + 3 * r + 0], s1x * ps + qs * q0);
            atomicAdd(&sums[(size_t)src * 40 + 16 + 3 * r + 1], s1y * ps + qs * q1);
            atomicAdd(&sums[(size_t)src * 40 + 16 + 3 * r + 2], s1z * ps + qs * q2);
        }
        if (r == 0) atomicAdd(&cnts[src], 1.0f);
        #undef WW
        __syncthreads();
    }
}

// -----------------------------------------------------------------------------
// y = sums/max(cnt,1) + atom; accumulate BN statistics (wave-shuffle reduced)
// -----------------------------------------------------------------------------
__global__ __launch_bounds__(256)
void finalize_stats_kernel(const float* __restrict__ sums,
                           const float* __restrict__ cnts,
                           const float* __restrict__ atom,
                           float* __restrict__ y,
                           float* __restrict__ stats)
{
    const int n = blockIdx.x * blockDim.x + threadIdx.x;
    float yv[40];
    if (n < N_NODES) {
        const float rinv = 1.0f / fmaxf(cnts[n], 1.0f);
        const float4* s4 = (const float4*)(sums + (size_t)n * 40);
        const float4* a4 = (const float4*)(atom + (size_t)n * 40);
        float4* y4 = (float4*)(y + (size_t)n * 40);
        #pragma unroll
        for (int r = 0; r < 10; ++r) {
            const float4 sv = s4[r];
            const float4 av = a4[r];
            float4 o;
            o.x = sv.x * rinv + av.x;
            o.y = sv.y * rinv + av.y;
            o.z = sv.z * rinv + av.z;
            o.w = sv.w * rinv + av.w;
            y4[r] = o;
            yv[r * 4 + 0] = o.x; yv[r * 4 + 1] = o.y;
            yv[r * 4 + 2] = o.z; yv[r * 4 + 3] = o.w;
        }
    } else {
        #pragma unroll
        for (int s = 0; s < 40; ++s) yv[s] = 0.0f;
    }

    float contrib[40];
    #pragma unroll
    for (int j = 0; j < 16; ++j) {
        contrib[j]      = yv[j];
        contrib[16 + j] = yv[j] * yv[j];
    }
    #pragma unroll
    for (int j = 0; j < 8; ++j) {
        const float vx = yv[16 + 3 * j], vy = yv[17 + 3 * j], vz = yv[18 + 3 * j];
        contrib[32 + j] = (vx * vx + vy * vy + vz * vz) * (1.0f / 3.0f);
    }
    #pragma unroll
    for (int s = 0; s < 40; ++s) {
        float v = contrib[s];
        #pragma unroll
        for (int off = 32; off > 0; off >>= 1) v += __shfl_xor(v, off);
        if ((threadIdx.x & 63) == 0) atomicAdd(&stats[s], v);
    }
}

__global__ __launch_bounds__(256)
void apply_bn_kernel(float* __restrict__ y,
                     const float* __restrict__ stats,
                     const float* __restrict__ bnw,
                     const float* __restrict__ bnb)
{
    const int idx = blockIdx.x * blockDim.x + threadIdx.x;
    if (idx >= N_NODES * 40) return;
    const int o = idx % 40;
    const float invN = 1.0f / (float)N_NODES;
    const float v = y[idx];
    float out;
    if (o < MUL0) {
        const float mean  = stats[o] * invN;
        const float var   = stats[16 + o] * invN - mean * mean;
        const float scale = rsqrtf(var + EPS) * bnw[o];
        out = (v - mean) * scale + bnb[o];
    } else {
        const int j = (o - 16) / 3;
        const float vn = stats[32 + j] * invN;
        out = v * (rsqrtf(vn + EPS) * bnw[16 + j]);
    }
    y[idx] = out;
}

// -----------------------------------------------------------------------------
extern "C" void kernel_launch(void* const* d_in, const int* in_sizes, int n_in,
                              void* d_out, int out_size, void* d_ws, size_t ws_size,
                              hipStream_t stream)
{
    const float* atom = (const float*)d_in[0];
    const float* ef   = (const float*)d_in[1];
    const float* esh  = (const float*)d_in[2];
    const int*   eidx = (const int*)d_in[3];
    const float* W1   = (const float*)d_in[4];
    const float* b1   = (const float*)d_in[5];
    const float* W2   = (const float*)d_in[6];
    const float* b2   = (const float*)d_in[7];
    const float* bnw  = (const float*)d_in[8];
    const float* bnb  = (const float*)d_in[9];
    float* out = (float*)d_out;

    float* sums  = (float*)d_ws;                       // N_NODES*40
    float* cnts  = sums + (size_t)N_NODES * 40;        // N_NODES
    float* stats = cnts + N_NODES;                     // 40
    unsigned short* W1F = (unsigned short*)(stats + 40);   // 4096 bf16
    unsigned short* W2F = W1F + 4096;                      // 36864 bf16

    const int* e_dst = eidx;
    const int* e_src = eidx + N_EDGES;

    prep_frags<<<256, 256, 0, stream>>>(W1, W2, W1F, W2F, sums);

    fused_edge_kernel<<<N_EDGES / BM, THREADS, 0, stream>>>(
        atom, ef, esh, e_dst, e_src, W1F, b1, W2F, b2, sums, cnts);

    finalize_stats_kernel<<<(N_NODES + 255) / 256, 256, 0, stream>>>(
        sums, cnts, atom, out, stats);

    apply_bn_kernel<<<(N_NODES * 40 + 255) / 256, 256, 0, stream>>>(
        out, stats, bnw, bnb);
}